// Round 4
// baseline (215.159 us; speedup 1.0000x reference)
//
#include <hip/hip_runtime.h>
#include <math.h>

#define NUM_CLASSES 35
#define ROWS_PER_TILE 256
#define THREADS 256
#define GRID_BLOCKS 512                              // 2 blocks/CU (72KB LDS each)
#define TILE_FLOATS (ROWS_PER_TILE * NUM_CLASSES)    // 8960
#define FULL16 8                                     // 8 x 16B per thread = 32768 B
#define REM_OFF_B (FULL16 * THREADS * 16)            // 32768; remainder 3072 B = 256 x 12B

// Stage one 256x35 fp32 tile global->LDS. Exactly 9 VMEM instructions per
// thread (8 x 16B + 1 x 12B), uniform across all waves, so a counted
// s_waitcnt vmcnt(N) is exact. Layout is linear (wave-uniform base + lane*sz).
__device__ __forceinline__ void stage_tile(const float* __restrict__ src,
                                           float* __restrict__ dstlds, int tid)
{
    #pragma unroll
    for (int i = 0; i < FULL16; ++i) {
        const int byteoff = (tid + i * THREADS) * 16;
        __builtin_amdgcn_global_load_lds(
            (const __attribute__((address_space(1))) void*)((const char*)src + byteoff),
            (__attribute__((address_space(3))) void*)((char*)dstlds + byteoff),
            16, 0, 0);
    }
    {
        const int byteoff = REM_OFF_B + tid * 12;
        __builtin_amdgcn_global_load_lds(
            (const __attribute__((address_space(1))) void*)((const char*)src + byteoff),
            (__attribute__((address_space(3))) void*)((char*)dstlds + byteoff),
            12, 0, 0);
    }
}

// Persistent pass 1: 512 blocks x 8 tiles, double-buffered LDS, counted vmcnt.
// Race-fix history (round 3 failed with absmax=inf):
//  (a) fence BETWEEN prologue's 11 VMEM ops and iter-0's 11 VMEM ops — without
//      it the scheduler may interleave the two groups and vmcnt(11) then
//      leaves a PROLOGUE op in flight -> compute on unstaged (poisoned) LDS.
//  (b) s_waitcnt lgkmcnt(0) before the buffer-reuse barrier — raw s_barrier
//      does NOT drain this wave's pending ds_reads (unlike __syncthreads),
//      so the next tile's DMA could overwrite cur under a pending read.
// (Round-1 post-mortem: no agent-scope acquire per block — cache storm.)
__global__ __launch_bounds__(256) void fuzzy_loss_pass1(
    const float* __restrict__ logits,
    const int* __restrict__ targets,
    const int* __restrict__ turns,
    float* __restrict__ block_sums,
    int tiles_per_block)
{
    __shared__ float buf0[TILE_FLOATS];   // 35840 B
    __shared__ float buf1[TILE_FLOATS];   // 35840 B  -> 71680 B total, 2 blocks/CU
    __shared__ float wsum[THREADS / 64];

    const int tid   = threadIdx.x;
    const int tile0 = blockIdx.x * tiles_per_block;

    // ---- Prologue: tile 0 scalar loads + stage = exactly 11 VMEM ops ----
    int tgt = targets[tile0 * ROWS_PER_TILE + tid];
    int trn = turns[tile0 * ROWS_PER_TILE + tid];
    stage_tile(logits + (size_t)tile0 * TILE_FLOATS, buf0, tid);
    asm volatile("" ::: "memory");   // (a) pin prologue group BEFORE iter-0 group

    float vacc = 0.0f;

    for (int k = 0; k < tiles_per_block; ++k) {
        float* cur = (k & 1) ? buf1 : buf0;
        float* nxt = (k & 1) ? buf0 : buf1;

        int ntgt = 0, ntrn = 0;
        if (k < tiles_per_block - 1) {
            const int nrow = (tile0 + k + 1) * ROWS_PER_TILE + tid;
            ntgt = targets[nrow];                 // +2 VMEM
            ntrn = turns[nrow];
            stage_tile(logits + (size_t)(tile0 + k + 1) * TILE_FLOATS, nxt, tid); // +9
            // Leave exactly this iteration's 11 ops in flight; everything
            // older (tile k's stage + its scalar loads) is retired.
            asm volatile("s_waitcnt vmcnt(11)" ::: "memory");
        } else {
            asm volatile("s_waitcnt vmcnt(0)" ::: "memory");   // epilogue drain
        }
        __builtin_amdgcn_s_barrier();          // all waves' tile-k staging done
        asm volatile("" ::: "memory");         // no LDS reads hoisted above barrier

        // ---- Compute tile k (row tid of cur) ----
        const float* r = cur + tid * NUM_CLASSES;  // bank=(3t+j)%32 -> 2-way, free
        float s = 0.0f;
        #pragma unroll
        for (int j = 0; j < NUM_CLASSES; ++j) s += __expf(r[j]);
        const float loss = __logf(s) - r[tgt];     // logits~N(0,1): no overflow
        float w = fmaf(0.05f, (float)trn, 0.4f);   // 0.7 + 0.05*(t-6)
        w = fminf(fmaxf(w, 0.7f), 1.0f);
        vacc = fmaf(loss, w, vacc);

        if (k < tiles_per_block - 1) {
            // (b) this wave's ds_reads must have DELIVERED (data in regs)
            // before we signal the barrier that allows cur to be overwritten.
            asm volatile("s_waitcnt lgkmcnt(0)" ::: "memory");
            __builtin_amdgcn_s_barrier();
            asm volatile("" ::: "memory");
            tgt = ntgt; trn = ntrn;
        }
    }

    // ---- Block reduction: wave64 shuffle -> LDS -> single store ----
    #pragma unroll
    for (int off = 32; off > 0; off >>= 1)
        vacc += __shfl_down(vacc, off, 64);
    if ((tid & 63) == 0) wsum[tid >> 6] = vacc;
    __syncthreads();
    if (tid == 0)
        block_sums[blockIdx.x] = wsum[0] + wsum[1] + wsum[2] + wsum[3];
}

// Pass 2: one block reduces 512 partials, writes mean to out[0].
__global__ __launch_bounds__(256) void fuzzy_loss_pass2(
    const float* __restrict__ block_sums,
    float* __restrict__ out,
    int nblocks, float inv_B)
{
    const int tid = threadIdx.x;
    float v = 0.0f;
    const float4* src = (const float4*)block_sums;   // 512 -> 128 float4
    for (int i = tid; i < nblocks / 4; i += 256) {
        float4 f = src[i];
        v += (f.x + f.y) + (f.z + f.w);
    }
    #pragma unroll
    for (int off = 32; off > 0; off >>= 1)
        v += __shfl_down(v, off, 64);

    __shared__ float wsum[4];
    if ((tid & 63) == 0) wsum[tid >> 6] = v;
    __syncthreads();
    if (tid == 0)
        out[0] = (wsum[0] + wsum[1] + wsum[2] + wsum[3]) * inv_B;
}

extern "C" void kernel_launch(void* const* d_in, const int* in_sizes, int n_in,
                              void* d_out, int out_size, void* d_ws, size_t ws_size,
                              hipStream_t stream) {
    const float* logits  = (const float*)d_in[0];
    const int*   targets = (const int*)d_in[1];
    const int*   turns   = (const int*)d_in[2];
    float*       out     = (float*)d_out;
    float*       partial = (float*)d_ws;

    const int B = in_sizes[1];                     // 1048576
    const int total_tiles = B / ROWS_PER_TILE;     // 4096
    const int tpb = total_tiles / GRID_BLOCKS;     // 8

    fuzzy_loss_pass1<<<GRID_BLOCKS, THREADS, 0, stream>>>(
        logits, targets, turns, partial, tpb);
    fuzzy_loss_pass2<<<1, 256, 0, stream>>>(partial, out, GRID_BLOCKS, 1.0f / (float)B);
}

// Round 6
// 211.325 us; speedup vs baseline: 1.0181x; 1.0181x over previous
//
#include <hip/hip_runtime.h>
#include <math.h>

#define NUM_CLASSES 35
#define ROWS_PER_BLOCK 256
#define WAVE_BYTES (64 * NUM_CLASSES * 4)   // 8960 B staged per wave

// Pass 1: 4096 blocks x 256 threads, 4 blocks/CU (36KB LDS), 16 waves/CU.
// Each WAVE stages its own 64-row (8960 B) LDS slice via global_load_lds and
// waits only on its own vmcnt — NO mid-kernel barrier. Waves free-run as
// independent streams (the structure that lets pure fills hit 86% of HBM
// peak); no cross-wave LDS hazard since slices are disjoint.
//
// Session history:
//  - r1: last-block fusion w/ agent-scope ACQ_REL = buffer_inv storm (228us).
//  - r3/r4: persistent 2-blocks/CU double-buffer + counted vmcnt = race, then
//    (fixed) 215us — occupancy loss + barrier coupling beat the pipelining
//    gain. Inter-block TLP already covers the drain (m99/m114 lesson).
//  - r5: infra failure (container), this source never ran — resubmitted as-is.
__global__ __launch_bounds__(256) void fuzzy_loss_pass1(
    const float* __restrict__ logits,
    const int* __restrict__ targets,
    const int* __restrict__ turns,
    float* __restrict__ block_sums)
{
    __shared__ float lds[ROWS_PER_BLOCK * NUM_CLASSES];  // 35840 B
    __shared__ float wsum[ROWS_PER_BLOCK / 64];

    const int tid  = threadIdx.x;
    const int lane = tid & 63;
    const int w    = tid >> 6;
    const int row0 = blockIdx.x * ROWS_PER_BLOCK;
    const int row  = row0 + tid;

    // Hoisted per-row scalar loads: retire under the same vmcnt(0) below,
    // latency overlapped with the staging stream.
    const int tgt = targets[row];   // coalesced 4B
    const int trn = turns[row];     // coalesced 4B

    // ---- Per-wave staging: 8960 B = 8 x (64 lanes x 16B) + 48 lanes x 16B ----
    // LDS dest = wave-uniform base + lane*16 (linear), matching global src.
    {
        const char* srcb = (const char*)(logits + (size_t)row0 * NUM_CLASSES)
                         + w * WAVE_BYTES;
        char* dstb = (char*)lds + w * WAVE_BYTES;
        #pragma unroll
        for (int i = 0; i < 8; ++i) {
            const int off = i * 1024 + lane * 16;
            __builtin_amdgcn_global_load_lds(
                (const __attribute__((address_space(1))) void*)(srcb + off),
                (__attribute__((address_space(3))) void*)(dstb + off),
                16, 0, 0);
        }
        if (lane < 48) {    // remainder 768 B
            const int off = 8192 + lane * 16;
            __builtin_amdgcn_global_load_lds(
                (const __attribute__((address_space(1))) void*)(srcb + off),
                (__attribute__((address_space(3))) void*)(dstb + off),
                16, 0, 0);
        }
    }
    // Wait for THIS wave's 11 VMEM ops only — no block barrier.
    asm volatile("s_waitcnt vmcnt(0)" ::: "memory");

    // ---- Per-thread row compute ----
    // Row base: w*2240 + lane*35 = tid*35 floats. Bank = (3*tid + j) % 32:
    // 2-way alias only, which is free on CDNA4.
    const float* r = lds + tid * NUM_CLASSES;

    float s = 0.0f;
    #pragma unroll
    for (int j = 0; j < NUM_CLASSES; ++j) s += __expf(r[j]);

    const float xt = r[tgt];                   // dynamic LDS read
    float loss = __logf(s) - xt;               // logits~N(0,1): no overflow

    float wgt = fmaf(0.05f, (float)trn, 0.4f); // 0.7 + 0.05*(t-6)
    wgt = fminf(fmaxf(wgt, 0.7f), 1.0f);
    float v = loss * wgt;

    // ---- Reduction: wave64 shuffle -> LDS -> single store ----
    #pragma unroll
    for (int off = 32; off > 0; off >>= 1)
        v += __shfl_down(v, off, 64);
    if (lane == 0) wsum[w] = v;
    __syncthreads();   // only barrier in the kernel (end-of-block reduce)
    if (tid == 0)
        block_sums[blockIdx.x] = wsum[0] + wsum[1] + wsum[2] + wsum[3];
}

// Pass 2: one block reduces 4096 partials, writes mean to out[0].
__global__ __launch_bounds__(256) void fuzzy_loss_pass2(
    const float* __restrict__ block_sums,
    float* __restrict__ out,
    int nblocks, float inv_B)
{
    const int tid = threadIdx.x;
    float v = 0.0f;
    const float4* src = (const float4*)block_sums;   // 4096 -> 1024 float4
    for (int i = tid; i < nblocks / 4; i += 256) {
        float4 f = src[i];
        v += (f.x + f.y) + (f.z + f.w);
    }
    #pragma unroll
    for (int off = 32; off > 0; off >>= 1)
        v += __shfl_down(v, off, 64);

    __shared__ float wsum[4];
    if ((tid & 63) == 0) wsum[tid >> 6] = v;
    __syncthreads();
    if (tid == 0)
        out[0] = (wsum[0] + wsum[1] + wsum[2] + wsum[3]) * inv_B;
}

extern "C" void kernel_launch(void* const* d_in, const int* in_sizes, int n_in,
                              void* d_out, int out_size, void* d_ws, size_t ws_size,
                              hipStream_t stream) {
    const float* logits  = (const float*)d_in[0];
    const int*   targets = (const int*)d_in[1];
    const int*   turns   = (const int*)d_in[2];
    float*       out     = (float*)d_out;
    float*       partial = (float*)d_ws;

    const int B = in_sizes[1];                 // 1048576, divisible by 256
    const int blocks = B / ROWS_PER_BLOCK;     // 4096

    fuzzy_loss_pass1<<<blocks, ROWS_PER_BLOCK, 0, stream>>>(logits, targets, turns, partial);
    fuzzy_loss_pass2<<<1, 256, 0, stream>>>(partial, out, blocks, 1.0f / (float)B);
}